// Round 17
// baseline (243.811 us; speedup 1.0000x reference)
//
#include <hip/hip_runtime.h>
#include <math.h>

typedef int v4i  __attribute__((ext_vector_type(4)));
typedef int v16i __attribute__((ext_vector_type(16)));

#define DIM 4096
#define BT 256              // gemm output tile (BT x BT)
#define BK 64               // K-tile bytes (int8)
#define ATILE (BT * BK)     // 16384 B per operand tile
#define BUFSZ (2 * ATILE)   // 32768 B per buffer (A | B)

// ---------------------------------------------------------------------------
// async global->LDS 16B copy (wave-uniform base + lane*16 destination rule)
// ---------------------------------------------------------------------------
__device__ __forceinline__ void async16(const void* g, void* l) {
    __builtin_amdgcn_global_load_lds((__attribute__((address_space(1))) void*)(g),
                                     (__attribute__((address_space(3))) void*)(l),
                                     16, 0, 0);
}

// raw barrier / counted waitcnt (T4): no implicit vmcnt(0) drain.
#define VMCNT(N) asm volatile("s_waitcnt vmcnt(" #N ")" ::: "memory")
#define BARRIER() asm volatile("s_barrier" ::: "memory")

// Bank swizzle over the 4 16B chunks of a 64B row (R10, best-measured).
__device__ __forceinline__ int swzC(int r) {
    return ((r >> 1) & 3) ^ ((r >> 3) & 3);
}

// in-register 16-point FWHT (unnormalized Sylvester), all indices static
__device__ __forceinline__ void fwht16(float* v) {
    #pragma unroll
    for (int mm = 1; mm < 16; mm <<= 1)
        #pragma unroll
        for (int i = 0; i < 16; ++i)
            if (!(i & mm)) {
                const float a = v[i], b = v[i | mm];
                v[i] = a + b; v[i | mm] = a - b;
            }
}

// ---------------------------------------------------------------------------
// prep v2 — shuffle-free FWHT via H256 = H16 (x) H16 (Kronecker):
//   phase 1: thread t loads 16 CONSECUTIVE floats, in-register FWHT-16
//            (stages m=1..8), stores to LDS padded (+1 float per 16).
//   phase 2: thread t takes block b=t>>4, lane k=t&15, reads the stride-16
//            set {k+16j}, in-register FWHT-16 (stages m=16..128), computes
//            row max, writes values back to the SAME (self-owned) slots.
//   phase 3: thread t re-reads 16 consecutive positions, quantizes with
//            rinv = 7/m, packs 16 int8, one coalesced 16B global store.
// All LDS patterns are 2-way-aliased max (free, m136).  Zero ds_bpermute
// (the old kernel's ~100 wave64 shuffles/thread were the latency suspect).
// Scale contract identical to the passing R11 prep: unnormalized values are
// 16x ref; stored s = (m*0.0625)/7; q = clamp(rint(f*rinv)).
// Blocks >= 4096: weight narrowing, unchanged (streaming, coalesced).
// ---------------------------------------------------------------------------
__global__ __launch_bounds__(256) void prep(const float* __restrict__ x,
                                            const int* __restrict__ w,
                                            signed char* __restrict__ q,
                                            signed char* __restrict__ w8,
                                            float* __restrict__ scales) {
    if (blockIdx.x >= 4096) {
        int i = (blockIdx.x - 4096) * 256 + threadIdx.x;
        int4 v = ((const int4*)w)[i];
        char4 c;
        c.x = (signed char)v.x; c.y = (signed char)v.y;
        c.z = (signed char)v.z; c.w = (signed char)v.w;
        ((char4*)w8)[i] = c;
        return;
    }
    __shared__ float lds[DIM + DIM / 16];      // 4096 + 256 floats (17 KB)
    __shared__ float sm[4];

    const int row = blockIdx.x;
    const int t   = threadIdx.x;
    const int lane = t & 63, wave = t >> 6;

    // phase 1: 16 consecutive floats at offset 16t
    float v[16];
    {
        const float4* xr4 = (const float4*)(x + (size_t)row * DIM + t * 16);
        #pragma unroll
        for (int i = 0; i < 4; ++i) {
            const float4 f4 = xr4[i];
            v[4 * i + 0] = f4.x; v[4 * i + 1] = f4.y;
            v[4 * i + 2] = f4.z; v[4 * i + 3] = f4.w;
        }
    }
    fwht16(v);                                  // stages m=1..8
    // padded store: float pos p=16t+i -> addr p + (p>>4) = 17t + i
    #pragma unroll
    for (int i = 0; i < 16; ++i) lds[17 * t + i] = v[i];
    __syncthreads();

    // phase 2: block b=t>>4, k=t&15; pos p = b*256 + k + 16j -> addr b*272+k+17j
    const int p2base = (t >> 4) * 272 + (t & 15);
    #pragma unroll
    for (int j = 0; j < 16; ++j) v[j] = lds[p2base + 17 * j];
    fwht16(v);                                  // stages m=16..128 (final, 16x ref)

    float m = 0.0f;
    #pragma unroll
    for (int j = 0; j < 16; ++j) m = fmaxf(m, fabsf(v[j]));
    #pragma unroll
    for (int d = 32; d; d >>= 1) m = fmaxf(m, __shfl_xor(m, d, 64));
    if (lane == 0) sm[wave] = m;
    // write back to the same self-owned slots (no barrier needed: 1:1)
    #pragma unroll
    for (int j = 0; j < 16; ++j) lds[p2base + 17 * j] = v[j];
    __syncthreads();                            // covers sm[] AND write-back

    m = fmaxf(fmaxf(sm[0], sm[1]), fmaxf(sm[2], sm[3]));
    const float s = (m * 0.0625f) / 7.0f;       // identical to verified contract
    if (t == 0) scales[row] = s;
    const float rinv = 7.0f / m;

    // phase 3: 16 consecutive positions p=16t+i at addr 17t+i; quant; pack.
    #pragma unroll
    for (int i = 0; i < 16; ++i) v[i] = lds[17 * t + i];
    int pk[4];
    #pragma unroll
    for (int u = 0; u < 4; ++u) {
        int b0 = min(7, max(-8, (int)rintf(v[4 * u + 0] * rinv)));
        int b1 = min(7, max(-8, (int)rintf(v[4 * u + 1] * rinv)));
        int b2 = min(7, max(-8, (int)rintf(v[4 * u + 2] * rinv)));
        int b3 = min(7, max(-8, (int)rintf(v[4 * u + 3] * rinv)));
        pk[u] = (b0 & 255) | ((b1 & 255) << 8) | ((b2 & 255) << 16) | (b3 << 24);
    }
    int4 outv; outv.x = pk[0]; outv.y = pk[1]; outv.z = pk[2]; outv.w = pk[3];
    ((int4*)(q + (size_t)row * DIM))[t] = outv;
}

// ---------------------------------------------------------------------------
// int8 GEMM — EXACT R10 kernel (best measured: 86.7 us, MfmaUtil 33%).
// 256x256 tile, BK=64, 8 waves (2M x 4N), quad-buffered LDS, 3-deep
// prefetch, counted VMCNT(8), raw barriers, setprio, XCD rectangles.
// Held frozen this round so the prep delta reads cleanly from the total.
// ---------------------------------------------------------------------------
__global__ __launch_bounds__(512, 2) void gemm_q8(const signed char* __restrict__ A,
                                                  const signed char* __restrict__ B,
                                                  const float* __restrict__ rowScale,
                                                  const float* __restrict__ wscale,
                                                  const float* __restrict__ bias,
                                                  float* __restrict__ out) {
    __shared__ __align__(16) signed char S[4 * BUFSZ];   // 128 KB

    const int flat = blockIdx.y * gridDim.x + blockIdx.x;
    const int xcd  = flat & 7;
    const int idx  = flat >> 3;                 // 0..31
    const int bm   = ((xcd >> 1) << 2) + (idx & 3);
    const int bn   = ((xcd & 1) << 3) + (idx >> 2);

    const int t = threadIdx.x;
    const int lane = t & 63;
    const int wave = t >> 6;                    // 0..7
    const int wm = (wave >> 2) * 128;           // 2 waves in M
    const int wn = (wave & 3) * 64;             // 4 waves in N
    const int l31 = lane & 31, lh = lane >> 5;

    const signed char* ga[2];
    const signed char* gb[2];
    int ldsA[2], ldsB[2];
    #pragma unroll
    for (int h = 0; h < 2; ++h) {
        const int cidx = t + 512 * h;           // 0..1023
        const int row  = cidx >> 2;             // 0..255
        const int g    = (cidx & 3) ^ swzC(row);
        ga[h] = A + (size_t)(bm * BT + row) * DIM + g * 16;
        gb[h] = B + (size_t)(bn * BT + row) * DIM + g * 16;
        ldsA[h] = cidx * 16;
        ldsB[h] = ATILE + cidx * 16;
    }

    int offA[4][2], offB[2][2];
    #pragma unroll
    for (int i = 0; i < 4; ++i)
        #pragma unroll
        for (int s = 0; s < 2; ++s) {
            const int r = wm + i * 32 + l31;
            offA[i][s] = r * BK + (((2 * s + lh) ^ swzC(r)) * 16);
        }
    #pragma unroll
    for (int j = 0; j < 2; ++j)
        #pragma unroll
        for (int s = 0; s < 2; ++s) {
            const int c = wn + j * 32 + l31;
            offB[j][s] = ATILE + c * BK + (((2 * s + lh) ^ swzC(c)) * 16);
        }

    v16i acc[4][2] = {};

#define STAGE(P) do {                                                          \
        async16(ga[0], &S[(P) * BUFSZ + ldsA[0]]); ga[0] += BK;                \
        async16(ga[1], &S[(P) * BUFSZ + ldsA[1]]); ga[1] += BK;                \
        async16(gb[0], &S[(P) * BUFSZ + ldsB[0]]); gb[0] += BK;                \
        async16(gb[1], &S[(P) * BUFSZ + ldsB[1]]); gb[1] += BK;                \
    } while (0)

#define COMPUTE(P) do {                                                        \
        __builtin_amdgcn_s_setprio(1);                                         \
        _Pragma("unroll")                                                      \
        for (int s = 0; s < 2; ++s) {                                          \
            const v4i a0 = *(const v4i*)&S[(P) * BUFSZ + offA[0][s]];          \
            const v4i a1 = *(const v4i*)&S[(P) * BUFSZ + offA[1][s]];          \
            const v4i a2 = *(const v4i*)&S[(P) * BUFSZ + offA[2][s]];          \
            const v4i a3 = *(const v4i*)&S[(P) * BUFSZ + offA[3][s]];          \
            const v4i b0 = *(const v4i*)&S[(P) * BUFSZ + offB[0][s]];          \
            const v4i b1 = *(const v4i*)&S[(P) * BUFSZ + offB[1][s]];          \
            acc[0][0] = __builtin_amdgcn_mfma_i32_32x32x32_i8(a0, b0, acc[0][0], 0, 0, 0); \
            acc[0][1] = __builtin_amdgcn_mfma_i32_32x32x32_i8(a0, b1, acc[0][1], 0, 0, 0); \
            acc[1][0] = __builtin_amdgcn_mfma_i32_32x32x32_i8(a1, b0, acc[1][0], 0, 0, 0); \
            acc[1][1] = __builtin_amdgcn_mfma_i32_32x32x32_i8(a1, b1, acc[1][1], 0, 0, 0); \
            acc[2][0] = __builtin_amdgcn_mfma_i32_32x32x32_i8(a2, b0, acc[2][0], 0, 0, 0); \
            acc[2][1] = __builtin_amdgcn_mfma_i32_32x32x32_i8(a2, b1, acc[2][1], 0, 0, 0); \
            acc[3][0] = __builtin_amdgcn_mfma_i32_32x32x32_i8(a3, b0, acc[3][0], 0, 0, 0); \
            acc[3][1] = __builtin_amdgcn_mfma_i32_32x32x32_i8(a3, b1, acc[3][1], 0, 0, 0); \
        }                                                                      \
        __builtin_amdgcn_s_setprio(0);                                         \
    } while (0)

    STAGE(0); STAGE(1); STAGE(2);
    #pragma unroll 1
    for (int it = 0; it < 15; ++it) {
        VMCNT(8); BARRIER(); STAGE(3); COMPUTE(0);
        VMCNT(8); BARRIER(); STAGE(0); COMPUTE(1);
        VMCNT(8); BARRIER(); STAGE(1); COMPUTE(2);
        VMCNT(8); BARRIER(); STAGE(2); COMPUTE(3);
    }
    VMCNT(8); BARRIER(); STAGE(3); COMPUTE(0);
    VMCNT(8); BARRIER();           COMPUTE(1);
    VMCNT(4); BARRIER();           COMPUTE(2);
    VMCNT(0); BARRIER();           COMPUTE(3);

#undef STAGE
#undef COMPUTE

    // epilogue: out[n,o] = acc * sx[n] * ws[o] + bias[o]
    // C/D: col = lane&31, row = (reg&3) + 8*(reg>>2) + 4*(lane>>5)  [m74/m101]
    #pragma unroll
    for (int j = 0; j < 2; ++j) {
        const int col = bn * BT + wn + j * 32 + l31;
        const float ws = wscale[col];
        const float bs = bias[col];
        #pragma unroll
        for (int i = 0; i < 4; ++i) {
            const int rb = bm * BT + wm + i * 32 + 4 * lh;
            #pragma unroll
            for (int r = 0; r < 16; ++r) {
                const int row = rb + (r & 3) + 8 * (r >> 2);
                out[(size_t)row * DIM + col] =
                    ((float)acc[i][j][r] * rowScale[row]) * ws + bs;
            }
        }
    }
}

// ---------------------------------------------------------------------------
extern "C" void kernel_launch(void* const* d_in, const int* in_sizes, int n_in,
                              void* d_out, int out_size, void* d_ws, size_t ws_size,
                              hipStream_t stream) {
    const float* x      = (const float*)d_in[0];
    const int*   wint   = (const int*)d_in[1];
    const float* wscale = (const float*)d_in[2];
    const float* bias   = (const float*)d_in[3];
    float* out = (float*)d_out;

    signed char* q8 = (signed char*)d_ws;                         // 16 MB
    signed char* w8 = q8 + (size_t)DIM * DIM;                     // 16 MB
    float* sx = (float*)(w8 + (size_t)DIM * DIM);                 // 16 KB

    prep<<<4096 + 16384, 256, 0, stream>>>(x, wint, q8, w8, sx);
    gemm_q8<<<dim3(DIM / BT, DIM / BT), 512, 0, stream>>>(q8, w8, sx, wscale, bias, out);
}